// Round 4
// baseline (362.214 us; speedup 1.0000x reference)
//
#include <hip/hip_runtime.h>
#include <hip/hip_bf16.h>
#include <math.h>

// Problem constants (CausalSelfAttention_84928683311105)
#define B_  2
#define T_  2048
#define C_  2048
#define NH_ 16
#define NKV_ 4
#define HD_ 128
#define NREP_ (NH_/NKV_)     // 4

// fused QKV output layout: [B*T, 3072] ; q @ 0, k @ 2048, v @ 2560
#define QKVLD 3072
#define KOFF  2048
#define VOFF  2560

// q scale: (1/sqrt(d))^2 folded = 1/128, times log2(e) so scores are in
// log2 units and softmax exp is a single native v_exp_f32.
#define QSCALE 0.01127105500694502f

typedef __bf16 bf16x8 __attribute__((ext_vector_type(8)));
typedef float  f32x4  __attribute__((ext_vector_type(4)));
typedef float  f32x16 __attribute__((ext_vector_type(16)));

__device__ inline void gload_lds16(const void* g, void* l) {
    __builtin_amdgcn_global_load_lds((const __attribute__((address_space(1))) void*)g,
                                     (__attribute__((address_space(3))) void*)l, 16, 0, 0);
}

// ---------------------------------------------------------------------------
// cast fp32 -> bf16, 8 elems/thread
// ---------------------------------------------------------------------------
__global__ __launch_bounds__(256) void cast_bf16(const float* __restrict__ src,
                                                 __bf16* __restrict__ dst)
{
    size_t i = ((size_t)blockIdx.x * 256 + threadIdx.x) * 8;
    float4 a = *(const float4*)&src[i];
    float4 b = *(const float4*)&src[i + 4];
    union { __bf16 h[8]; uint4 u; } pk;
    pk.h[0] = (__bf16)a.x; pk.h[1] = (__bf16)a.y; pk.h[2] = (__bf16)a.z; pk.h[3] = (__bf16)a.w;
    pk.h[4] = (__bf16)b.x; pk.h[5] = (__bf16)b.y; pk.h[6] = (__bf16)b.z; pk.h[7] = (__bf16)b.w;
    *(uint4*)&dst[i] = pk.u;
}

// ---------------------------------------------------------------------------
// merged transpose-cast of Wq|Wk|Wv into wqkvT [3072, 2048] bf16.
// col-tile ct: 0..63 -> Wq (ncols 2048), 64..79 -> Wk, 80..95 -> Wv.
// ---------------------------------------------------------------------------
__global__ __launch_bounds__(256) void wtrans_qkv(const float* __restrict__ Wq,
                                                  const float* __restrict__ Wk,
                                                  const float* __restrict__ Wv,
                                                  __bf16* __restrict__ dst)
{
    __shared__ float tl[32][33];
    int ct = blockIdx.x;
    int k0 = blockIdx.y * 32;
    const float* src;
    int ncols, c0, dr0;
    if (ct < 64)      { src = Wq; ncols = 2048; c0 = ct * 32;        dr0 = ct * 32; }
    else if (ct < 80) { src = Wk; ncols = 512;  c0 = (ct - 64) * 32; dr0 = KOFF + (ct - 64) * 32; }
    else              { src = Wv; ncols = 512;  c0 = (ct - 80) * 32; dr0 = VOFF + (ct - 80) * 32; }

    int tid = threadIdx.x;
    int r  = tid >> 3;
    int c4 = (tid & 7) * 4;
    float4 v = *(const float4*)&src[(size_t)(k0 + r) * ncols + c0 + c4];
    tl[r][c4] = v.x; tl[r][c4 + 1] = v.y; tl[r][c4 + 2] = v.z; tl[r][c4 + 3] = v.w;
    __syncthreads();
    union { __bf16 h[4]; uint2 u; } pk;
#pragma unroll
    for (int j = 0; j < 4; ++j) pk.h[j] = (__bf16)tl[c4 + j][r];
    *(uint2*)&dst[(size_t)(dr0 + r) * 2048 + k0 + c4] = pk.u;
}

// plain transpose-cast for Wp
__global__ __launch_bounds__(256) void wtrans(const float* __restrict__ src,
                                              __bf16* __restrict__ dst, int ncols)
{
    __shared__ float tl[32][33];
    int n0 = blockIdx.x * 32;
    int k0 = blockIdx.y * 32;
    int tid = threadIdx.x;
    int r  = tid >> 3;
    int c4 = (tid & 7) * 4;
    float4 v = *(const float4*)&src[(size_t)(k0 + r) * ncols + n0 + c4];
    tl[r][c4] = v.x; tl[r][c4 + 1] = v.y; tl[r][c4 + 2] = v.z; tl[r][c4 + 3] = v.w;
    __syncthreads();
    union { __bf16 h[4]; uint2 u; } pk;
#pragma unroll
    for (int j = 0; j < 4; ++j) pk.h[j] = (__bf16)tl[c4 + j][r];
    *(uint2*)&dst[(size_t)(n0 + r) * 2048 + k0 + c4] = pk.u;
}

// ---------------------------------------------------------------------------
// bf16 MFMA GEMM, single-barrier double-buffered: C = A(MxK) @ Bt^T, Bt [N,K].
// 128x128 tile, BK=32, 4 waves, global_load_lds(16B) prefetch into alt buffer.
// ---------------------------------------------------------------------------
template<typename TOUT>
__global__ __launch_bounds__(256) void gemm_bt(const __bf16* __restrict__ A,
                                               const __bf16* __restrict__ Bt,
                                               TOUT* __restrict__ C,
                                               int M, int N, int K, int ldc)
{
    __shared__ __bf16 As[2][128 * 32];   // [m][k]
    __shared__ __bf16 Bs[2][128 * 32];   // [n][k]

    const int tid  = threadIdx.x;
    const int wv   = tid >> 6;
    const int lane = tid & 63;
    const int grp  = lane >> 4;
    const int id16 = lane & 15;
    const int wr   = wv >> 1;
    const int wc   = wv & 1;

    const int row0 = blockIdx.y * 128;
    const int col0 = blockIdx.x * 128;

    const int sm = tid >> 2;
    const int sk = (tid & 3) << 3;

    const __bf16* ga0 = A  + (size_t)(row0 + sm) * K + sk;
    const __bf16* ga1 = A  + (size_t)(row0 + 64 + sm) * K + sk;
    const __bf16* gb0 = Bt + (size_t)(col0 + sm) * K + sk;
    const __bf16* gb1 = Bt + (size_t)(col0 + 64 + sm) * K + sk;

    f32x4 acc[4][4];
    const f32x4 fz = {0.f, 0.f, 0.f, 0.f};
#pragma unroll
    for (int i = 0; i < 4; ++i)
#pragma unroll
        for (int j = 0; j < 4; ++j) acc[i][j] = fz;

    const int nk = K >> 5;

    // prologue: stage tile 0 into buf 0
    {
        __bf16* a0 = &As[0][wv << 9];
        __bf16* b0 = &Bs[0][wv << 9];
        gload_lds16(ga0, a0);
        gload_lds16(ga1, a0 + 2048);
        gload_lds16(gb0, b0);
        gload_lds16(gb1, b0 + 2048);
    }

    for (int kt = 0; kt < nk; ++kt) {
        const int bufc = kt & 1;
        asm volatile("s_waitcnt vmcnt(0)" ::: "memory");
        __syncthreads();

        if (kt + 1 < nk) {
            const int kb = (kt + 1) << 5;
            __bf16* a0 = &As[1 - bufc][wv << 9];
            __bf16* b0 = &Bs[1 - bufc][wv << 9];
            gload_lds16(ga0 + kb, a0);
            gload_lds16(ga1 + kb, a0 + 2048);
            gload_lds16(gb0 + kb, b0);
            gload_lds16(gb1 + kb, b0 + 2048);
        }

        bf16x8 af[4], bfr[4];
#pragma unroll
        for (int i = 0; i < 4; ++i)
            af[i] = *(const bf16x8*)&As[bufc][((wr << 6) + (i << 4) + id16) * 32 + (grp << 3)];
#pragma unroll
        for (int j = 0; j < 4; ++j)
            bfr[j] = *(const bf16x8*)&Bs[bufc][((wc << 6) + (j << 4) + id16) * 32 + (grp << 3)];
#pragma unroll
        for (int i = 0; i < 4; ++i)
#pragma unroll
            for (int j = 0; j < 4; ++j)
                acc[i][j] = __builtin_amdgcn_mfma_f32_16x16x32_bf16(af[i], bfr[j], acc[i][j], 0, 0, 0);
    }

#pragma unroll
    for (int i = 0; i < 4; ++i) {
        int gr = row0 + (wr << 6) + (i << 4) + (grp << 2);
#pragma unroll
        for (int j = 0; j < 4; ++j) {
            int gc = col0 + (wc << 6) + (j << 4) + id16;
#pragma unroll
            for (int r = 0; r < 4; ++r) {
                if constexpr (sizeof(TOUT) == 4)
                    C[(size_t)(gr + r) * ldc + gc] = acc[i][j][r];
                else
                    C[(size_t)(gr + r) * ldc + gc] = (TOUT)acc[i][j][r];
            }
        }
    }
}

// ---------------------------------------------------------------------------
// RoPE + RMSNorm in-place on bf16 head-vectors inside the strided qkv buffer.
// ---------------------------------------------------------------------------
__global__ __launch_bounds__(256) void rope_rms_b(__bf16* __restrict__ base,
                                                  const float* __restrict__ cosb,
                                                  const float* __restrict__ sinb,
                                                  int nheads, float scale)
{
    int wid  = blockIdx.x * 4 + (threadIdx.x >> 6);
    int lane = threadIdx.x & 63;
    int bt = wid / nheads;
    int hd = wid % nheads;
    int t  = bt % T_;

    __bf16* p = base + (size_t)bt * QKVLD + hd * HD_;
    float c = cosb[t * 64 + lane];
    float s = sinb[t * 64 + lane];
    float x1 = (float)p[lane];
    float x2 = (float)p[lane + 64];
    float r1 = x1 * c - x2 * s;
    float r2 = x1 * s + x2 * c;
    float ss = r1 * r1 + r2 * r2;
#pragma unroll
    for (int off = 32; off; off >>= 1) ss += __shfl_xor(ss, off, 64);
    float inv = rsqrtf(ss * (1.f / 128.f) + 1e-6f) * scale;
    p[lane]      = (__bf16)(r1 * inv);
    p[lane + 64] = (__bf16)(r2 * inv);
}

// ---------------------------------------------------------------------------
// Transpose V out of qkv: -> vt [B,NKV,128,T] bf16.
// ---------------------------------------------------------------------------
__global__ __launch_bounds__(256) void vtrans(const __bf16* __restrict__ qkv,
                                              __bf16* __restrict__ vt)
{
    __shared__ __bf16 tl[32][HD_ + 8];
    int bx  = blockIdx.x;
    int st  = bx & 63;
    int bkv = bx >> 6;
    int b = bkv >> 2, kv = bkv & 3;
    int s0 = st << 5;
    int tid = threadIdx.x;
    {
        int s = tid >> 3;
        int d = (tid & 7) << 4;
        const __bf16* src = qkv + (size_t)(b * T_ + s0 + s) * QKVLD + VOFF + kv * HD_ + d;
        *(bf16x8*)&tl[s][d]     = *(const bf16x8*)src;
        *(bf16x8*)&tl[s][d + 8] = *(const bf16x8*)(src + 8);
    }
    __syncthreads();
    {
        int d  = tid >> 1;
        int sh = (tid & 1) << 4;
        __bf16 tmp[16];
#pragma unroll
        for (int j = 0; j < 16; ++j) tmp[j] = tl[sh + j][d];
        __bf16* dst = vt + ((size_t)(b * NKV_ + kv) * HD_ + d) * T_ + s0 + sh;
        *(bf16x8*)dst       = *(bf16x8*)&tmp[0];
        *(bf16x8*)(dst + 8) = *(bf16x8*)&tmp[8];
    }
}

// ---------------------------------------------------------------------------
// Flash attention v6: occupancy push. v5 measured 18% occupancy (grid 512 =
// 2 blocks/CU hard cap; 64KB LDS also caps at 2) while MFMA needs only ~5%
// of cycles -> latency-bound serial chain with nothing to overlap.
//
// v6: KVBLK=32 (K dbuf 16KB + V-half dbuf 8KB = 24KB LDS) and a d-split:
// each block computes a 64-wide half of O (dh), duplicating only the QK
// MFMA (cheap). Grid = 8p * 2role * 2dh * 32bh = 1024 = exactly 4/CU,
// __launch_bounds__(256,4) -> 16 waves/CU target.
//
// Work split per pair p (hi=15-p, lo=p): 32-key tiles: NHt=4hi+4, NLt=4lo+4,
// sum 68. Role A: hi tiles [0,34). Role B: hi [34,NHt) then lo [0,NLt),
// 34 tiles each -> uniform durations. Fixed-max softmax keeps partials
// additive; combine kernel sums (o,l) for the hi tile. d-halves write
// disjoint 64-d slices of the same partial buffers (no extra storage).
// ---------------------------------------------------------------------------
__global__ __launch_bounds__(256, 4) void attn32(const __bf16* __restrict__ qkv,
                                                 const __bf16* __restrict__ vbT,
                                                 __bf16* __restrict__ y,
                                                 float* __restrict__ pOA,
                                                 float* __restrict__ pOB,
                                                 float* __restrict__ pLA,
                                                 float* __restrict__ pLB)
{
    __shared__ __bf16 Ks[2][32 * 128];   // [key][d] , chunk16 ^ (row&15)
    __shared__ __bf16 Vs[2][16 * 128];   // row r: d_local r,r+16,r+32,r+48 x 32 keys

    const int tid  = threadIdx.x;
    const int wv   = tid >> 6;
    const int lane = tid & 63;
    const int l31  = lane & 31;
    const int h32  = lane >> 5;

    const int bx   = blockIdx.x;         // 1024 = ((p*2+role)*2+dh)*32 + bh
    const int bh   = bx & 31;
    const int dh   = (bx >> 5) & 1;
    const int role = (bx >> 6) & 1;
    const int p    = bx >> 7;            // 0..7
    const int b    = bh >> 4;
    const int h    = bh & 15;
    const int kv   = h >> 2;
    const int slot = p * 32 + bh;

    const int hi  = 15 - p;              // 8..15
    const int lo  = p;                   // 0..7
    const int NHt = 64 - 4 * p;          // hi 32-key tiles (36..64)
    const int tts = role ? (NHt - 34) : 99;   // B's phase switch (2..30)

    // k-tile index for loop step t (phase-aware)
    auto KT = [&](int t) { return role ? (t < tts ? 34 + t : t - tts) : t; };

    int qw0 = hi * 128 + wv * 32;        // wave's first q row (phase 0)
    int qme = qw0 + l31;

    // ---- staging offsets: LDS dest linear, global source pre-swizzled ----
    uint koff0, koff1, voff;
    {
        int r0 = wv * 8 + (lane >> 4);               // K rows, instr 0
        int c  = lane & 15;
        koff0 = (uint)(r0 * (QKVLD * 2) + ((c ^ (r0 & 15)) << 4));
        int r1 = r0 + 4;                             // K rows, instr 1
        koff1 = (uint)(r1 * (QKVLD * 2) + ((c ^ (r1 & 15)) << 4));
        int rv = wv * 4 + (lane >> 4);               // V row 0..15
        int cs = c ^ rv;                             // rv&15 == rv
        voff = (uint)((dh * 64 + rv + ((cs >> 2) << 4)) * (T_ * 2) + ((cs & 3) << 4));
    }
    const char* kg = (const char*)(qkv + (size_t)b * T_ * QKVLD + KOFF + kv * HD_);
    const char* vg = (const char*)(vbT + ((size_t)(b * NKV_ + kv) * HD_) * T_);

#define STAGE(BUF, KN)                                                        \
    {                                                                         \
        const char* kp = kg + (size_t)(KN) * (32 * QKVLD * 2);                \
        const char* vp = vg + (size_t)(KN) * (32 * 2);                        \
        __bf16* kl = &Ks[BUF][(wv * 8) * 128];                                \
        gload_lds16(kp + koff0, kl);                                          \
        gload_lds16(kp + koff1, kl + 512);                                    \
        gload_lds16(vp + voff, &Vs[BUF][(wv * 4) * 128]);                     \
    }

    // ---- Q fragments (B operand: col=q=l31, k=d); qf2 reloaded at switch ----
    const __bf16* qp  = qkv + (size_t)(b * T_ + hi * 128 + wv * 32 + l31) * QKVLD + h * HD_ + h32 * 8;
    const __bf16* qp2 = qkv + (size_t)(b * T_ + lo * 128 + wv * 32 + l31) * QKVLD + h * HD_ + h32 * 8;
    bf16x8 qf[8];
#pragma unroll
    for (int s = 0; s < 8; ++s) qf[s] = *(const bf16x8*)(qp + s * 16);

    f32x16 o[2];
#pragma unroll
    for (int dt = 0; dt < 2; ++dt)
#pragma unroll
        for (int r = 0; r < 16; ++r) o[dt][r] = 0.f;
    float l_p = 0.f;

#define STORE_PARTIAL(PO, PL)                                                   \
    {                                                                           \
        float lsum = l_p + __shfl_xor(l_p, 32, 64);                             \
        int qloc = wv * 32 + l31;                                               \
        float* po = (PO) + ((size_t)slot * 128 + qloc) * 128 + dh * 64;         \
        _Pragma("unroll")                                                       \
        for (int dt = 0; dt < 2; ++dt)                                          \
            _Pragma("unroll")                                                   \
            for (int g = 0; g < 4; ++g) {                                       \
                float4 f = {o[dt][4 * g + 0], o[dt][4 * g + 1],                 \
                            o[dt][4 * g + 2], o[dt][4 * g + 3]};                \
                *(float4*)&po[dt * 32 + 8 * g + 4 * h32] = f;                   \
            }                                                                   \
        if (h32 == 0 && dh == 0) (PL)[slot * 128 + qloc] = lsum;                \
    }

    // prologue: stage first k-tile into buf 0
    STAGE(0, KT(0));

    for (int tt = 0; tt < 34; ++tt) {
        const int bufc = tt & 1;
        asm volatile("s_waitcnt vmcnt(0)" ::: "memory");
        __syncthreads();

        if (tt + 1 < 34) {
            int kn = KT(tt + 1);
            STAGE(1 - bufc, kn);
        }

        // B's phase switch: flush hi partial, reset state, swap to lo
        if (role && tt == tts) {
            STORE_PARTIAL(pOB, pLB);
#pragma unroll
            for (int dt = 0; dt < 2; ++dt)
#pragma unroll
                for (int r = 0; r < 16; ++r) o[dt][r] = 0.f;
            l_p = 0.f;
#pragma unroll
            for (int s = 0; s < 8; ++s) qf[s] = *(const bf16x8*)(qp2 + s * 16);
            qw0 = lo * 128 + wv * 32;
            qme = qw0 + l31;
        }

        const int s0 = KT(tt) << 5;
        if (s0 > qw0 + 31) continue;     // wave fully masked (prefetch already issued)

        // ---- QK^T swapped: S^T[key][q], one 32-key C tile ----
        f32x16 S;
#pragma unroll
        for (int r = 0; r < 16; ++r) S[r] = 0.f;
        const __bf16* Kb = Ks[bufc];
        __builtin_amdgcn_s_setprio(1);
#pragma unroll
        for (int s = 0; s < 8; ++s) {
            bf16x8 kf = *(const bf16x8*)&Kb[l31 * 128 + (((s * 2 + h32) ^ (l31 & 15)) << 3)];
            S = __builtin_amdgcn_mfma_f32_32x32x16_bf16(kf, qf[s], S, 0, 0, 0);
        }
        __builtin_amdgcn_s_setprio(0);

        // ---- softmax numerators in-register; pack to bf16 pair words ----
        // lane holds keys k(i) = 2*(i&1) + 8*(i>>1) + 4*h32 (+s0) for its q col.
        const bool domask = (s0 + 31 > qw0);
        uint w[8];
#pragma unroll
        for (int i = 0; i < 8; ++i) {
            float e0 = exp2f(S[2 * i]);
            float e1 = exp2f(S[2 * i + 1]);
            if (domask) {
                int k0 = s0 + 2 * (i & 1) + 8 * (i >> 1) + 4 * h32;
                if (k0     > qme) e0 = 0.f;
                if (k0 + 1 > qme) e1 = 0.f;
            }
            l_p += e0 + e1;
            union { __bf16 h2[2]; uint u; } pk;
            pk.h2[0] = (__bf16)e0; pk.h2[1] = (__bf16)e1;
            w[i] = pk.u;
        }

        // ---- half-exchange: lane needs keys 16*ks + 8*h32 + 0..7 as P^T B-frag ----
        uint sw[8];
#pragma unroll
        for (int i = 0; i < 8; ++i) sw[i] = (uint)__shfl_xor((int)w[i], 32, 64);

        union U8 { uint u[4]; bf16x8 v; };
        bf16x8 pf[2];
#pragma unroll
        for (int ks = 0; ks < 2; ++ks) {
            const int b4 = 4 * ks;
            U8 t;
            if (h32 == 0) {
                t.u[0] = w[b4];      t.u[1] = w[b4 + 1];
                t.u[2] = sw[b4];     t.u[3] = sw[b4 + 1];
            } else {
                t.u[0] = sw[b4 + 2]; t.u[1] = sw[b4 + 3];
                t.u[2] = w[b4 + 2];  t.u[3] = w[b4 + 3];
            }
            pf[ks] = t.v;
        }

        // ---- PV (d-half): O^T[d][q] += V^T[d][key] P^T[key][q] ----
        const __bf16* Vb = Vs[bufc];
        __builtin_amdgcn_s_setprio(1);
#pragma unroll
        for (int dt = 0; dt < 2; ++dt) {
            const int rv = l31 & 15;
            const int gg = dt * 2 + (l31 >> 4);      // d_local = rv + gg*16 = dt*32 + l31
#pragma unroll
            for (int ks = 0; ks < 2; ++ks) {
                bf16x8 vf = *(const bf16x8*)&Vb[rv * 128 + ((((gg << 2) + (ks << 1) + h32) ^ rv) << 3)];
                o[dt] = __builtin_amdgcn_mfma_f32_32x32x16_bf16(vf, pf[ks], o[dt], 0, 0, 0);
            }
        }
        __builtin_amdgcn_s_setprio(0);
    }

    // ---- final epilogue ----
    if (role == 0) {
        STORE_PARTIAL(pOA, pLA);
    } else {
        // lo tile: normalize and write y directly (this block's d-half)
        float l  = l_p + __shfl_xor(l_p, 32, 64);
        float inv = 1.f / l;
        __bf16* yp = y + (size_t)(b * T_ + qw0 + l31) * C_ + h * HD_ + dh * 64;
#pragma unroll
        for (int dt = 0; dt < 2; ++dt)
#pragma unroll
            for (int g = 0; g < 4; ++g) {
                union { __bf16 h4[4]; uint2 u; } pk;
#pragma unroll
                for (int e = 0; e < 4; ++e) pk.h4[e] = (__bf16)(o[dt][4 * g + e] * inv);
                *(uint2*)&yp[dt * 32 + 8 * g + 4 * h32] = pk.u;
            }
    }
#undef STORE_PARTIAL
#undef STAGE
}

// ---------------------------------------------------------------------------
// Combine hi-tile partials: y = (oA + oB) / (lA + lB).  256 blocks x 256 thr.
// ---------------------------------------------------------------------------
__global__ __launch_bounds__(256) void attn_combine(const float* __restrict__ pOA,
                                                    const float* __restrict__ pOB,
                                                    const float* __restrict__ pLA,
                                                    const float* __restrict__ pLB,
                                                    __bf16* __restrict__ y)
{
    int slot = blockIdx.x;               // p*32 + bh
    int p  = slot >> 5, bh = slot & 31;
    int b  = bh >> 4,   h  = bh & 15;
    int hi = 15 - p;
    int t  = threadIdx.x;
    int q  = t >> 1;                     // 0..127
    int dh = (t & 1) << 6;               // 0 or 64

    float inv = 1.f / (pLA[slot * 128 + q] + pLB[slot * 128 + q]);
    size_t base = ((size_t)slot * 128 + q) * 128 + dh;
    __bf16* yp = y + (size_t)(b * T_ + hi * 128 + q) * C_ + h * HD_ + dh;
#pragma unroll
    for (int d0 = 0; d0 < 64; d0 += 8) {
        float4 a0 = *(const float4*)&pOA[base + d0];
        float4 a1 = *(const float4*)&pOA[base + d0 + 4];
        float4 b0 = *(const float4*)&pOB[base + d0];
        float4 b1 = *(const float4*)&pOB[base + d0 + 4];
        union { __bf16 h8[8]; uint4 u; } pk;
        pk.h8[0] = (__bf16)((a0.x + b0.x) * inv);
        pk.h8[1] = (__bf16)((a0.y + b0.y) * inv);
        pk.h8[2] = (__bf16)((a0.z + b0.z) * inv);
        pk.h8[3] = (__bf16)((a0.w + b0.w) * inv);
        pk.h8[4] = (__bf16)((a1.x + b1.x) * inv);
        pk.h8[5] = (__bf16)((a1.y + b1.y) * inv);
        pk.h8[6] = (__bf16)((a1.z + b1.z) * inv);
        pk.h8[7] = (__bf16)((a1.w + b1.w) * inv);
        *(uint4*)&yp[d0] = pk.u;
    }
}

// ---------------------------------------------------------------------------
extern "C" void kernel_launch(void* const* d_in, const int* in_sizes, int n_in,
                              void* d_out, int out_size, void* d_ws, size_t ws_size,
                              hipStream_t stream)
{
    const float* x    = (const float*)d_in[0];
    const float* cosb = (const float*)d_in[1];
    const float* sinb = (const float*)d_in[2];
    const float* Wq   = (const float*)d_in[3];
    const float* Wk   = (const float*)d_in[4];
    const float* Wv   = (const float*)d_in[5];
    const float* Wp   = (const float*)d_in[6];
    float* out = (float*)d_out;

    const int M = B_ * T_;   // 4096

    // workspace: xb | qkv | wqkvT | wpT | vt | y | pOB   (~101 MB)
    // pOA aliases xb (dead after gemm1, exactly 16.78 MB); pL* alias wqkvT.
    char* w = (char*)d_ws;
    __bf16* xb    = (__bf16*)w;  w += (size_t)M * C_ * 2;
    __bf16* qkv   = (__bf16*)w;  w += (size_t)M * QKVLD * 2;
    __bf16* wqkvT = (__bf16*)w;  w += (size_t)QKVLD * C_ * 2;
    __bf16* wpT   = (__bf16*)w;  w += (size_t)C_ * C_ * 2;
    __bf16* vt    = (__bf16*)w;  w += (size_t)M * NKV_ * HD_ * 2;
    __bf16* y     = (__bf16*)w;  w += (size_t)M * C_ * 2;
    float*  pOB   = (float*)w;   // 8*32*128*128*4 = 16.78 MB
    float*  pOA   = (float*)xb;
    float*  pLA   = (float*)wqkvT;
    float*  pLB   = pLA + 8 * 32 * 128;

    // casts / transposes
    cast_bf16<<<(M * C_) / 2048, 256, 0, stream>>>(x, xb);
    wtrans_qkv<<<dim3(96, C_ / 32), 256, 0, stream>>>(Wq, Wk, Wv, wqkvT);
    wtrans<<<dim3(C_ / 32, C_ / 32), 256, 0, stream>>>(Wp, wpT, C_);

    // fused QKV projection (bf16 MFMA, dbuf)
    gemm_bt<__bf16><<<dim3(QKVLD / 128, M / 128), 256, 0, stream>>>(xb, wqkvT, qkv, M, QKVLD, C_, QKVLD);

    // RoPE + RMSNorm in-place (q gets 1/128 * log2e; k plain)
    rope_rms_b<<<(M * NH_) / 4, 256, 0, stream>>>(qkv, cosb, sinb, NH_, QSCALE);
    rope_rms_b<<<(M * NKV_) / 4, 256, 0, stream>>>(qkv + KOFF, cosb, sinb, NKV_, 1.0f);

    // V transpose to [B,KV,128,T]
    vtrans<<<B_ * NKV_ * (T_ / 32), 256, 0, stream>>>(qkv, vt);

    // flash attention v6: KVBLK=32 + d-split, 1024 blocks = 4/CU
    attn32<<<1024, 256, 0, stream>>>(qkv, vt, y, pOA, pOB, pLA, pLB);
    attn_combine<<<256, 256, 0, stream>>>(pOA, pOB, pLA, pLB, y);

    // output projection (bf16 MFMA, fp32 out, dbuf)
    gemm_bt<float><<<dim3(C_ / 128, M / 128), 256, 0, stream>>>(y, wpT, out, M, C_, C_, C_);
}

// Round 5
// 326.534 us; speedup vs baseline: 1.1093x; 1.1093x over previous
//
#include <hip/hip_runtime.h>
#include <hip/hip_bf16.h>
#include <math.h>

// Problem constants (CausalSelfAttention_84928683311105)
#define B_  2
#define T_  2048
#define C_  2048
#define NH_ 16
#define NKV_ 4
#define HD_ 128
#define NREP_ (NH_/NKV_)     // 4

// fused QKV output layout: [B*T, 3072] ; q @ 0, k @ 2048, v @ 2560
#define QKVLD 3072
#define KOFF  2048
#define VOFF  2560

// q scale: (1/sqrt(d))^2 folded = 1/128, times log2(e) so scores are in
// log2 units and softmax exp is a single native v_exp_f32.
#define QSCALE 0.01127105500694502f

typedef __bf16 bf16x8 __attribute__((ext_vector_type(8)));
typedef float  f32x4  __attribute__((ext_vector_type(4)));
typedef float  f32x16 __attribute__((ext_vector_type(16)));

__device__ inline void gload_lds16(const void* g, void* l) {
    __builtin_amdgcn_global_load_lds((const __attribute__((address_space(1))) void*)g,
                                     (__attribute__((address_space(3))) void*)l, 16, 0, 0);
}

// ---------------------------------------------------------------------------
// cast fp32 -> bf16, 8 elems/thread
// ---------------------------------------------------------------------------
__global__ __launch_bounds__(256) void cast_bf16(const float* __restrict__ src,
                                                 __bf16* __restrict__ dst)
{
    size_t i = ((size_t)blockIdx.x * 256 + threadIdx.x) * 8;
    float4 a = *(const float4*)&src[i];
    float4 b = *(const float4*)&src[i + 4];
    union { __bf16 h[8]; uint4 u; } pk;
    pk.h[0] = (__bf16)a.x; pk.h[1] = (__bf16)a.y; pk.h[2] = (__bf16)a.z; pk.h[3] = (__bf16)a.w;
    pk.h[4] = (__bf16)b.x; pk.h[5] = (__bf16)b.y; pk.h[6] = (__bf16)b.z; pk.h[7] = (__bf16)b.w;
    *(uint4*)&dst[i] = pk.u;
}

// ---------------------------------------------------------------------------
// merged transpose-cast of Wq|Wk|Wv into wqkvT [3072, 2048] bf16.
// col-tile ct: 0..63 -> Wq (ncols 2048), 64..79 -> Wk, 80..95 -> Wv.
// ---------------------------------------------------------------------------
__global__ __launch_bounds__(256) void wtrans_qkv(const float* __restrict__ Wq,
                                                  const float* __restrict__ Wk,
                                                  const float* __restrict__ Wv,
                                                  __bf16* __restrict__ dst)
{
    __shared__ float tl[32][33];
    int ct = blockIdx.x;
    int k0 = blockIdx.y * 32;
    const float* src;
    int ncols, c0, dr0;
    if (ct < 64)      { src = Wq; ncols = 2048; c0 = ct * 32;        dr0 = ct * 32; }
    else if (ct < 80) { src = Wk; ncols = 512;  c0 = (ct - 64) * 32; dr0 = KOFF + (ct - 64) * 32; }
    else              { src = Wv; ncols = 512;  c0 = (ct - 80) * 32; dr0 = VOFF + (ct - 80) * 32; }

    int tid = threadIdx.x;
    int r  = tid >> 3;
    int c4 = (tid & 7) * 4;
    float4 v = *(const float4*)&src[(size_t)(k0 + r) * ncols + c0 + c4];
    tl[r][c4] = v.x; tl[r][c4 + 1] = v.y; tl[r][c4 + 2] = v.z; tl[r][c4 + 3] = v.w;
    __syncthreads();
    union { __bf16 h[4]; uint2 u; } pk;
#pragma unroll
    for (int j = 0; j < 4; ++j) pk.h[j] = (__bf16)tl[c4 + j][r];
    *(uint2*)&dst[(size_t)(dr0 + r) * 2048 + k0 + c4] = pk.u;
}

// plain transpose-cast for Wp
__global__ __launch_bounds__(256) void wtrans(const float* __restrict__ src,
                                              __bf16* __restrict__ dst, int ncols)
{
    __shared__ float tl[32][33];
    int n0 = blockIdx.x * 32;
    int k0 = blockIdx.y * 32;
    int tid = threadIdx.x;
    int r  = tid >> 3;
    int c4 = (tid & 7) * 4;
    float4 v = *(const float4*)&src[(size_t)(k0 + r) * ncols + n0 + c4];
    tl[r][c4] = v.x; tl[r][c4 + 1] = v.y; tl[r][c4 + 2] = v.z; tl[r][c4 + 3] = v.w;
    __syncthreads();
    union { __bf16 h[4]; uint2 u; } pk;
#pragma unroll
    for (int j = 0; j < 4; ++j) pk.h[j] = (__bf16)tl[c4 + j][r];
    *(uint2*)&dst[(size_t)(n0 + r) * 2048 + k0 + c4] = pk.u;
}

// ---------------------------------------------------------------------------
// bf16 MFMA GEMM, single-barrier double-buffered: C = A(MxK) @ Bt^T, Bt [N,K].
// 128x128 tile, BK=32, 4 waves, global_load_lds(16B) prefetch into alt buffer.
// ---------------------------------------------------------------------------
template<typename TOUT>
__global__ __launch_bounds__(256) void gemm_bt(const __bf16* __restrict__ A,
                                               const __bf16* __restrict__ Bt,
                                               TOUT* __restrict__ C,
                                               int M, int N, int K, int ldc)
{
    __shared__ __bf16 As[2][128 * 32];   // [m][k]
    __shared__ __bf16 Bs[2][128 * 32];   // [n][k]

    const int tid  = threadIdx.x;
    const int wv   = tid >> 6;
    const int lane = tid & 63;
    const int grp  = lane >> 4;
    const int id16 = lane & 15;
    const int wr   = wv >> 1;
    const int wc   = wv & 1;

    const int row0 = blockIdx.y * 128;
    const int col0 = blockIdx.x * 128;

    const int sm = tid >> 2;
    const int sk = (tid & 3) << 3;

    const __bf16* ga0 = A  + (size_t)(row0 + sm) * K + sk;
    const __bf16* ga1 = A  + (size_t)(row0 + 64 + sm) * K + sk;
    const __bf16* gb0 = Bt + (size_t)(col0 + sm) * K + sk;
    const __bf16* gb1 = Bt + (size_t)(col0 + 64 + sm) * K + sk;

    f32x4 acc[4][4];
    const f32x4 fz = {0.f, 0.f, 0.f, 0.f};
#pragma unroll
    for (int i = 0; i < 4; ++i)
#pragma unroll
        for (int j = 0; j < 4; ++j) acc[i][j] = fz;

    const int nk = K >> 5;

    // prologue: stage tile 0 into buf 0
    {
        __bf16* a0 = &As[0][wv << 9];
        __bf16* b0 = &Bs[0][wv << 9];
        gload_lds16(ga0, a0);
        gload_lds16(ga1, a0 + 2048);
        gload_lds16(gb0, b0);
        gload_lds16(gb1, b0 + 2048);
    }

    for (int kt = 0; kt < nk; ++kt) {
        const int bufc = kt & 1;
        asm volatile("s_waitcnt vmcnt(0)" ::: "memory");
        __syncthreads();

        if (kt + 1 < nk) {
            const int kb = (kt + 1) << 5;
            __bf16* a0 = &As[1 - bufc][wv << 9];
            __bf16* b0 = &Bs[1 - bufc][wv << 9];
            gload_lds16(ga0 + kb, a0);
            gload_lds16(ga1 + kb, a0 + 2048);
            gload_lds16(gb0 + kb, b0);
            gload_lds16(gb1 + kb, b0 + 2048);
        }

        bf16x8 af[4], bfr[4];
#pragma unroll
        for (int i = 0; i < 4; ++i)
            af[i] = *(const bf16x8*)&As[bufc][((wr << 6) + (i << 4) + id16) * 32 + (grp << 3)];
#pragma unroll
        for (int j = 0; j < 4; ++j)
            bfr[j] = *(const bf16x8*)&Bs[bufc][((wc << 6) + (j << 4) + id16) * 32 + (grp << 3)];
#pragma unroll
        for (int i = 0; i < 4; ++i)
#pragma unroll
            for (int j = 0; j < 4; ++j)
                acc[i][j] = __builtin_amdgcn_mfma_f32_16x16x32_bf16(af[i], bfr[j], acc[i][j], 0, 0, 0);
    }

#pragma unroll
    for (int i = 0; i < 4; ++i) {
        int gr = row0 + (wr << 6) + (i << 4) + (grp << 2);
#pragma unroll
        for (int j = 0; j < 4; ++j) {
            int gc = col0 + (wc << 6) + (j << 4) + id16;
#pragma unroll
            for (int r = 0; r < 4; ++r) {
                if constexpr (sizeof(TOUT) == 4)
                    C[(size_t)(gr + r) * ldc + gc] = acc[i][j][r];
                else
                    C[(size_t)(gr + r) * ldc + gc] = (TOUT)acc[i][j][r];
            }
        }
    }
}

// ---------------------------------------------------------------------------
// RoPE + RMSNorm in-place on bf16 head-vectors inside the strided qkv buffer.
// ---------------------------------------------------------------------------
__global__ __launch_bounds__(256) void rope_rms_b(__bf16* __restrict__ base,
                                                  const float* __restrict__ cosb,
                                                  const float* __restrict__ sinb,
                                                  int nheads, float scale)
{
    int wid  = blockIdx.x * 4 + (threadIdx.x >> 6);
    int lane = threadIdx.x & 63;
    int bt = wid / nheads;
    int hd = wid % nheads;
    int t  = bt % T_;

    __bf16* p = base + (size_t)bt * QKVLD + hd * HD_;
    float c = cosb[t * 64 + lane];
    float s = sinb[t * 64 + lane];
    float x1 = (float)p[lane];
    float x2 = (float)p[lane + 64];
    float r1 = x1 * c - x2 * s;
    float r2 = x1 * s + x2 * c;
    float ss = r1 * r1 + r2 * r2;
#pragma unroll
    for (int off = 32; off; off >>= 1) ss += __shfl_xor(ss, off, 64);
    float inv = rsqrtf(ss * (1.f / 128.f) + 1e-6f) * scale;
    p[lane]      = (__bf16)(r1 * inv);
    p[lane + 64] = (__bf16)(r2 * inv);
}

// ---------------------------------------------------------------------------
// Transpose V out of qkv: -> vt [B,NKV,128,T] bf16.
// ---------------------------------------------------------------------------
__global__ __launch_bounds__(256) void vtrans(const __bf16* __restrict__ qkv,
                                              __bf16* __restrict__ vt)
{
    __shared__ __bf16 tl[32][HD_ + 8];
    int bx  = blockIdx.x;
    int st  = bx & 63;
    int bkv = bx >> 6;
    int b = bkv >> 2, kv = bkv & 3;
    int s0 = st << 5;
    int tid = threadIdx.x;
    {
        int s = tid >> 3;
        int d = (tid & 7) << 4;
        const __bf16* src = qkv + (size_t)(b * T_ + s0 + s) * QKVLD + VOFF + kv * HD_ + d;
        *(bf16x8*)&tl[s][d]     = *(const bf16x8*)src;
        *(bf16x8*)&tl[s][d + 8] = *(const bf16x8*)(src + 8);
    }
    __syncthreads();
    {
        int d  = tid >> 1;
        int sh = (tid & 1) << 4;
        __bf16 tmp[16];
#pragma unroll
        for (int j = 0; j < 16; ++j) tmp[j] = tl[sh + j][d];
        __bf16* dst = vt + ((size_t)(b * NKV_ + kv) * HD_ + d) * T_ + s0 + sh;
        *(bf16x8*)dst       = *(bf16x8*)&tmp[0];
        *(bf16x8*)(dst + 8) = *(bf16x8*)&tmp[8];
    }
}

// ---------------------------------------------------------------------------
// Flash attention v7 = v5 structure (uniform 17-tile blocks, KVBLK=64,
// 32x32 MFMA, in-register softmax, additive partials) + three cuts:
//  1. tile-invariant LDS read offsets precomputed ONCE (off8[8] serves both
//     K and V reads; +8192 immediates for the second row-half), tt-loop
//     unrolled x2 so the LDS base is compile-time -> ~100 VALU/tile removed.
//  2. half-exchange uses 8 shfl_xor (select-before-shfl) instead of 16.
//  3. XCD clustering: cluster = bx&7 -> (b,kv), so all 64 blocks sharing a
//     1MB K/V panel land on one XCD's L2 (bx%8 = XCD round-robin).
// ---------------------------------------------------------------------------
__global__ __launch_bounds__(256, 2) void attn32(const __bf16* __restrict__ qkv,
                                                 const __bf16* __restrict__ vbT,
                                                 __bf16* __restrict__ y,
                                                 float* __restrict__ pOA,
                                                 float* __restrict__ pOB,
                                                 float* __restrict__ pLA,
                                                 float* __restrict__ pLB)
{
    __shared__ __bf16 Ks[2][64 * 128];   // [key][d] , chunk16 ^ (row&15)
    __shared__ __bf16 Vs[2][64 * 128];   // row r: d=r keys0..63 | d=r+64 keys0..63

    const int tid  = threadIdx.x;
    const int wv   = tid >> 6;
    const int lane = tid & 63;
    const int l31  = lane & 31;
    const int h32  = lane >> 5;

    // XCD-clustered decode: cluster (b,kv) = bx&7; member = bx>>3.
    const int bx   = blockIdx.x;         // 512
    const int b    = (bx >> 2) & 1;
    const int kv   = bx & 3;
    const int m    = bx >> 3;            // 0..63
    const int hh   = m & 3;
    const int role = (m >> 2) & 1;       // 0 = A (hi prefix), 1 = B (hi rest + lo)
    const int p    = m >> 3;             // 0..7
    const int h    = kv * 4 + hh;
    const int bh   = b * 16 + h;
    const int slot = p * 32 + bh;

    const int hi  = 15 - p;              // 8..15
    const int lo  = p;                   // 0..7
    const int tts = role ? (15 - 2 * p) : 99;   // B's phase switch (1..15)

    // k-tile index for loop step t (phase-aware)
    auto KT = [&](int t) { return role ? (t < tts ? 17 + t : t - tts) : t; };

    int qw0 = hi * 128 + wv * 32;        // wave's first q row (phase 0)
    int qme = qw0 + l31;

    // ---- staging offsets: LDS dest linear, global source pre-swizzled ----
    uint koff[4], voff[4];
#pragma unroll
    for (int i = 0; i < 4; ++i) {
        int r  = (wv * 4 + i) * 4 + (lane >> 4);   // LDS row 0..63
        int c  = lane & 15;                        // physical 16B chunk
        int cs = c ^ (r & 15);                     // logical chunk at source
        koff[i] = (uint)(r * (QKVLD * 2) + cs * 16);           // K[key=r][d=cs*8]
        int d   = r + ((cs >> 3) << 6);                        // V^T row packing
        voff[i] = (uint)(d * (T_ * 2) + (cs & 7) * 16);        // V^T[d][t=(cs&7)*8]
    }
    const char* kg = (const char*)(qkv + (size_t)b * T_ * QKVLD + KOFF + kv * HD_);
    const char* vg = (const char*)(vbT + ((size_t)(b * NKV_ + kv) * HD_) * T_);

    // ---- tile-invariant LDS read offsets (bytes). off8[s] serves both the
    // K-read (rows l31 / +8192 for rows 32+l31) and the V-read (s = 4a+ks,
    // +8192 for dt&1). row stride 256B; 16B-chunk XOR swizzle by l31&15. ----
    uint off8[8];
#pragma unroll
    for (int s = 0; s < 8; ++s)
        off8[s] = (uint)(l31 * 256 + ((((s << 1) + h32) ^ (l31 & 15)) << 4));

#define STAGE(BUF, KN)                                                        \
    {                                                                         \
        const char* kp = kg + (size_t)(KN) * (64 * QKVLD * 2);                \
        const char* vp = vg + (size_t)(KN) * (64 * 2);                        \
        __bf16* kl = &Ks[BUF][(wv * 4) * 512];                                \
        __bf16* vl = &Vs[BUF][(wv * 4) * 512];                                \
        _Pragma("unroll")                                                     \
        for (int i = 0; i < 4; ++i) gload_lds16(kp + koff[i], kl + i * 512);  \
        _Pragma("unroll")                                                     \
        for (int i = 0; i < 4; ++i) gload_lds16(vp + voff[i], vl + i * 512);  \
    }

    // ---- Q fragments: phase-0 (hi) and phase-1 (lo, role B) ----
    bf16x8 qf[8], qf2[8];
    {
        const __bf16* qp = qkv + (size_t)(b * T_ + hi * 128 + wv * 32 + l31) * QKVLD + h * HD_ + h32 * 8;
#pragma unroll
        for (int s = 0; s < 8; ++s) qf[s] = *(const bf16x8*)(qp + s * 16);
        const __bf16* qp2 = qkv + (size_t)(b * T_ + lo * 128 + wv * 32 + l31) * QKVLD + h * HD_ + h32 * 8;
#pragma unroll
        for (int s = 0; s < 8; ++s) qf2[s] = *(const bf16x8*)(qp2 + s * 16);
    }

    f32x16 o[4];
#pragma unroll
    for (int dt = 0; dt < 4; ++dt)
#pragma unroll
        for (int r = 0; r < 16; ++r) o[dt][r] = 0.f;
    float l_p = 0.f;

#define STORE_PARTIAL(PO, PL)                                                   \
    {                                                                           \
        float lsum = l_p + __shfl_xor(l_p, 32, 64);                             \
        int qloc = wv * 32 + l31;                                               \
        float* po = (PO) + ((size_t)slot * 128 + qloc) * 128;                   \
        _Pragma("unroll")                                                       \
        for (int dt = 0; dt < 4; ++dt)                                          \
            _Pragma("unroll")                                                   \
            for (int g = 0; g < 4; ++g) {                                       \
                float4 f = {o[dt][4 * g + 0], o[dt][4 * g + 1],                 \
                            o[dt][4 * g + 2], o[dt][4 * g + 3]};                \
                *(float4*)&po[dt * 32 + 8 * g + 4 * h32] = f;                   \
            }                                                                   \
        if (h32 == 0) (PL)[slot * 128 + qloc] = lsum;                           \
    }

    // one k-tile step; BUFC is a compile-time constant per instantiation
#define TILE_BODY(TT, BUFC)                                                     \
    {                                                                           \
        const int tt_ = (TT);                                                   \
        asm volatile("s_waitcnt vmcnt(0)" ::: "memory");                        \
        __syncthreads();                                                        \
        if (tt_ + 1 < 17) { int kn_ = KT(tt_ + 1); STAGE(1 - (BUFC), kn_); }    \
        if (role && tt_ == tts) {                                               \
            STORE_PARTIAL(pOB, pLB);                                            \
            _Pragma("unroll")                                                   \
            for (int dt = 0; dt < 4; ++dt)                                      \
                _Pragma("unroll")                                               \
                for (int r = 0; r < 16; ++r) o[dt][r] = 0.f;                    \
            l_p = 0.f;                                                          \
            _Pragma("unroll")                                                   \
            for (int s = 0; s < 8; ++s) qf[s] = qf2[s];                         \
            qw0 = lo * 128 + wv * 32;                                           \
            qme = qw0 + l31;                                                    \
        }                                                                       \
        const int s0 = KT(tt_) << 6;                                            \
        if (s0 <= qw0 + 31) {                                                   \
            const char* Kb = (const char*)&Ks[BUFC][0];                         \
            const char* Vb = (const char*)&Vs[BUFC][0];                         \
            f32x16 S0, S1;                                                      \
            _Pragma("unroll")                                                   \
            for (int r = 0; r < 16; ++r) { S0[r] = 0.f; S1[r] = 0.f; }          \
            __builtin_amdgcn_s_setprio(1);                                      \
            _Pragma("unroll")                                                   \
            for (int s = 0; s < 8; ++s) {                                       \
                bf16x8 kf0 = *(const bf16x8*)(Kb + off8[s]);                    \
                bf16x8 kf1 = *(const bf16x8*)(Kb + off8[s] + 8192);             \
                S0 = __builtin_amdgcn_mfma_f32_32x32x16_bf16(kf0, qf[s], S0, 0, 0, 0); \
                S1 = __builtin_amdgcn_mfma_f32_32x32x16_bf16(kf1, qf[s], S1, 0, 0, 0); \
            }                                                                   \
            __builtin_amdgcn_s_setprio(0);                                      \
            const bool domask = (s0 + 63 > qw0);                                \
            uint w[16];                                                         \
            _Pragma("unroll")                                                   \
            for (int i = 0; i < 8; ++i) {                                       \
                const int r0 = 2 * i;                                           \
                float e0 = exp2f(S0[r0]);                                       \
                float e1 = exp2f(S0[r0 + 1]);                                   \
                if (domask) {                                                   \
                    int k0 = s0 + (r0 & 3) + 8 * (r0 >> 2) + 4 * h32;           \
                    if (k0     > qme) e0 = 0.f;                                 \
                    if (k0 + 1 > qme) e1 = 0.f;                                 \
                }                                                               \
                l_p += e0 + e1;                                                 \
                union { __bf16 h2[2]; uint u; } pk;                             \
                pk.h2[0] = (__bf16)e0; pk.h2[1] = (__bf16)e1;                   \
                w[i] = pk.u;                                                    \
            }                                                                   \
            _Pragma("unroll")                                                   \
            for (int i = 0; i < 8; ++i) {                                       \
                const int r0 = 2 * i;                                           \
                float e0 = exp2f(S1[r0]);                                       \
                float e1 = exp2f(S1[r0 + 1]);                                   \
                if (domask) {                                                   \
                    int k0 = s0 + 32 + (r0 & 3) + 8 * (r0 >> 2) + 4 * h32;      \
                    if (k0     > qme) e0 = 0.f;                                 \
                    if (k0 + 1 > qme) e1 = 0.f;                                 \
                }                                                               \
                l_p += e0 + e1;                                                 \
                union { __bf16 h2[2]; uint u; } pk;                             \
                pk.h2[0] = (__bf16)e0; pk.h2[1] = (__bf16)e1;                   \
                w[8 + i] = pk.u;                                                \
            }                                                                   \
            union U8 { uint u[4]; bf16x8 v; };                                  \
            bf16x8 pf[4];                                                       \
            _Pragma("unroll")                                                   \
            for (int ks = 0; ks < 4; ++ks) {                                    \
                const int bsel = ((ks >> 1) << 3) + ((ks & 1) << 2);            \
                uint sa = h32 ? w[bsel]     : w[bsel + 2];                      \
                uint sb = h32 ? w[bsel + 1] : w[bsel + 3];                      \
                uint g0 = (uint)__shfl_xor((int)sa, 32, 64);                    \
                uint g1 = (uint)__shfl_xor((int)sb, 32, 64);                    \
                U8 t;                                                           \
                if (h32 == 0) {                                                 \
                    t.u[0] = w[bsel];     t.u[1] = w[bsel + 1];                 \
                    t.u[2] = g0;          t.u[3] = g1;                          \
                } else {                                                        \
                    t.u[0] = g0;          t.u[1] = g1;                          \
                    t.u[2] = w[bsel + 2]; t.u[3] = w[bsel + 3];                 \
                }                                                               \
                pf[ks] = t.v;                                                   \
            }                                                                   \
            __builtin_amdgcn_s_setprio(1);                                      \
            _Pragma("unroll")                                                   \
            for (int dt = 0; dt < 4; ++dt) {                                    \
                const int ab = (dt >> 1) << 2;                                  \
                const int hf = (dt & 1) * 8192;                                 \
                _Pragma("unroll")                                               \
                for (int ks = 0; ks < 4; ++ks) {                                \
                    bf16x8 vf = *(const bf16x8*)(Vb + off8[ab + ks] + hf);      \
                    o[dt] = __builtin_amdgcn_mfma_f32_32x32x16_bf16(vf, pf[ks], o[dt], 0, 0, 0); \
                }                                                               \
            }                                                                   \
            __builtin_amdgcn_s_setprio(0);                                      \
        }                                                                       \
    }

    // prologue: stage first k-tile into buf 0
    STAGE(0, KT(0));

    for (int tt = 0; tt < 16; tt += 2) {
        TILE_BODY(tt, 0);
        TILE_BODY(tt + 1, 1);
    }
    TILE_BODY(16, 0);

    // ---- final epilogue ----
    if (role == 0) {
        STORE_PARTIAL(pOA, pLA);
    } else {
        // lo tile: normalize and write y directly
        float l  = l_p + __shfl_xor(l_p, 32, 64);
        float inv = 1.f / l;
        __bf16* yp = y + (size_t)(b * T_ + qw0 + l31) * C_ + h * HD_;
#pragma unroll
        for (int dt = 0; dt < 4; ++dt)
#pragma unroll
            for (int g = 0; g < 4; ++g) {
                union { __bf16 h4[4]; uint2 u; } pk;
#pragma unroll
                for (int e = 0; e < 4; ++e) pk.h4[e] = (__bf16)(o[dt][4 * g + e] * inv);
                *(uint2*)&yp[dt * 32 + 8 * g + 4 * h32] = pk.u;
            }
    }
#undef TILE_BODY
#undef STORE_PARTIAL
#undef STAGE
}

// ---------------------------------------------------------------------------
// Combine hi-tile partials: y = (oA + oB) / (lA + lB).  256 blocks x 256 thr.
// ---------------------------------------------------------------------------
__global__ __launch_bounds__(256) void attn_combine(const float* __restrict__ pOA,
                                                    const float* __restrict__ pOB,
                                                    const float* __restrict__ pLA,
                                                    const float* __restrict__ pLB,
                                                    __bf16* __restrict__ y)
{
    int slot = blockIdx.x;               // p*32 + bh
    int p  = slot >> 5, bh = slot & 31;
    int b  = bh >> 4,   h  = bh & 15;
    int hi = 15 - p;
    int t  = threadIdx.x;
    int q  = t >> 1;                     // 0..127
    int dh = (t & 1) << 6;               // 0 or 64

    float inv = 1.f / (pLA[slot * 128 + q] + pLB[slot * 128 + q]);
    size_t base = ((size_t)slot * 128 + q) * 128 + dh;
    __bf16* yp = y + (size_t)(b * T_ + hi * 128 + q) * C_ + h * HD_ + dh;
#pragma unroll
    for (int d0 = 0; d0 < 64; d0 += 8) {
        float4 a0 = *(const float4*)&pOA[base + d0];
        float4 a1 = *(const float4*)&pOA[base + d0 + 4];
        float4 b0 = *(const float4*)&pOB[base + d0];
        float4 b1 = *(const float4*)&pOB[base + d0 + 4];
        union { __bf16 h8[8]; uint4 u; } pk;
        pk.h8[0] = (__bf16)((a0.x + b0.x) * inv);
        pk.h8[1] = (__bf16)((a0.y + b0.y) * inv);
        pk.h8[2] = (__bf16)((a0.z + b0.z) * inv);
        pk.h8[3] = (__bf16)((a0.w + b0.w) * inv);
        pk.h8[4] = (__bf16)((a1.x + b1.x) * inv);
        pk.h8[5] = (__bf16)((a1.y + b1.y) * inv);
        pk.h8[6] = (__bf16)((a1.z + b1.z) * inv);
        pk.h8[7] = (__bf16)((a1.w + b1.w) * inv);
        *(uint4*)&yp[d0] = pk.u;
    }
}

// ---------------------------------------------------------------------------
extern "C" void kernel_launch(void* const* d_in, const int* in_sizes, int n_in,
                              void* d_out, int out_size, void* d_ws, size_t ws_size,
                              hipStream_t stream)
{
    const float* x    = (const float*)d_in[0];
    const float* cosb = (const float*)d_in[1];
    const float* sinb = (const float*)d_in[2];
    const float* Wq   = (const float*)d_in[3];
    const float* Wk   = (const float*)d_in[4];
    const float* Wv   = (const float*)d_in[5];
    const float* Wp   = (const float*)d_in[6];
    float* out = (float*)d_out;

    const int M = B_ * T_;   // 4096

    // workspace: xb | qkv | wqkvT | wpT | vt | y | pOB   (~101 MB)
    // pOA aliases xb (dead after gemm1, exactly 16.78 MB); pL* alias wqkvT.
    char* w = (char*)d_ws;
    __bf16* xb    = (__bf16*)w;  w += (size_t)M * C_ * 2;
    __bf16* qkv   = (__bf16*)w;  w += (size_t)M * QKVLD * 2;
    __bf16* wqkvT = (__bf16*)w;  w += (size_t)QKVLD * C_ * 2;
    __bf16* wpT   = (__bf16*)w;  w += (size_t)C_ * C_ * 2;
    __bf16* vt    = (__bf16*)w;  w += (size_t)M * NKV_ * HD_ * 2;
    __bf16* y     = (__bf16*)w;  w += (size_t)M * C_ * 2;
    float*  pOB   = (float*)w;   // 8*32*128*128*4 = 16.78 MB
    float*  pOA   = (float*)xb;
    float*  pLA   = (float*)wqkvT;
    float*  pLB   = pLA + 8 * 32 * 128;

    // casts / transposes
    cast_bf16<<<(M * C_) / 2048, 256, 0, stream>>>(x, xb);
    wtrans_qkv<<<dim3(96, C_ / 32), 256, 0, stream>>>(Wq, Wk, Wv, wqkvT);
    wtrans<<<dim3(C_ / 32, C_ / 32), 256, 0, stream>>>(Wp, wpT, C_);

    // fused QKV projection (bf16 MFMA, dbuf)
    gemm_bt<__bf16><<<dim3(QKVLD / 128, M / 128), 256, 0, stream>>>(xb, wqkvT, qkv, M, QKVLD, C_, QKVLD);

    // RoPE + RMSNorm in-place (q gets 1/128 * log2e; k plain)
    rope_rms_b<<<(M * NH_) / 4, 256, 0, stream>>>(qkv, cosb, sinb, NH_, QSCALE);
    rope_rms_b<<<(M * NKV_) / 4, 256, 0, stream>>>(qkv + KOFF, cosb, sinb, NKV_, 1.0f);

    // V transpose to [B,KV,128,T]
    vtrans<<<B_ * NKV_ * (T_ / 32), 256, 0, stream>>>(qkv, vt);

    // flash attention v7: v5 structure + addr-hoist + XCD clustering
    attn32<<<512, 256, 0, stream>>>(qkv, vt, y, pOA, pOB, pLA, pLB);
    attn_combine<<<256, 256, 0, stream>>>(pOA, pOB, pLA, pLB, y);

    // output projection (bf16 MFMA, fp32 out, dbuf)
    gemm_bt<float><<<dim3(C_ / 128, M / 128), 256, 0, stream>>>(y, wpT, out, M, C_, C_, C_);
}